// Round 17
// baseline (272.051 us; speedup 1.0000x reference)
//
#include <hip/hip_runtime.h>
#include <hip/hip_bf16.h>

#define KK 7
#define NL1 8
#define NL2 8
#define IMG 128
#define REG 32            // region edge (pixels) per workgroup
#define RT 38             // o1 tile edge = REG + 6
#define O1P 40            // tile pitch (160B, 16B-aligned)
#define XR 44             // fused-kernel xt real rows/cols
#define XTP 44            // fused-kernel xt pitch
#define NBINS 64
#define NHB 16            // histogram blocks per region (4x4 of 8x8)

// Correctness contract (matches XLA-CPU f32 reference, verified round 6):
//  conv1: per-pixel strict sequential FMA chain, taps ordered dp->dq->c(fastest)
//  out1 : materialized as f32 (and zeroed outside the image = conv2 padding)
//  conv2: per-filter strict sequential FMA chain, taps ordered dp->dq
// Restructuring only changes WHERE operands come from, never per-chain order.
//
// Round-17: two-kernel split through d_ws (out1 roundtrip = 16.8MB ~ 5us HBM).
//  K1: conv1 exactly-once (no halo redundancy) + 8-ch batching: one 36-float
//      window feeds 672 FMAs (8x FMA:LDS ratio), 32 indep chains/thread.
//  K2: conv2+hist identical to round-11, but LDS = 8.1KB only ->
//      launch_bounds(256,8): up to 32 waves/CU to hide hist-atomic latency.
//  Fallback: round-11 fused kernel if ws_size < 16.8MB.

#define LDX12(dst, plane, row, col)                                          \
    { float4 t_;                                                             \
      t_ = *(const float4*)&xt[plane][row][col];                             \
      dst[0]=t_.x; dst[1]=t_.y; dst[2]=t_.z; dst[3]=t_.w;                    \
      t_ = *(const float4*)&xt[plane][row][(col)+4];                         \
      dst[4]=t_.x; dst[5]=t_.y; dst[6]=t_.z; dst[7]=t_.w;                    \
      t_ = *(const float4*)&xt[plane][row][(col)+8];                         \
      dst[8]=t_.x; dst[9]=t_.y; dst[10]=t_.z; dst[11]=t_.w; }

// =================== K1: conv1, exactly-once, 8-ch batched ===================
__global__ __launch_bounds__(256, 2) void pcanet_conv1(
    const float* __restrict__ x,    // (32,3,128,128)
    const float* __restrict__ w1,   // (8,3,7,7)
    float* __restrict__ o1g)        // (32,8,128,128) workspace
{
    const int tid = threadIdx.x;        // 0..255
    const int reg = blockIdx.x;         // 0..15 : 4x4 regions
    const int n   = blockIdx.y;         // image index
    const int P0  = (reg >> 2) * REG;
    const int Q0  = (reg & 3) * REG;

    __shared__ __align__(16) float xt[3][RT][O1P];   // 3x38x40 = 18.2KB

    // ---- x tile fill (halo 3): lane = col, rows wave-strided ----
    {
        const int lane = tid & 63, wv = tid >> 6;
        const float* xn = x + (size_t)n * 3 * IMG * IMG;
        const int gc = Q0 - 3 + lane;
        const bool cok = (gc >= 0 && gc < IMG);
        if (lane < O1P) {
            for (int c = 0; c < 3; ++c)
                for (int r = wv; r < RT; r += 4) {
                    int gr = P0 - 3 + r;
                    float v = 0.f;
                    if (cok && gr >= 0 && gr < IMG)
                        v = xn[((size_t)c * IMG + gr) * IMG + gc];
                    xt[c][r][lane] = v;
                }
        }
    }
    __syncthreads();

    // ---- conv1: thread owns (row, c1..c1+3) for ALL 8 channels ----
    const int row = tid >> 3;         // 0..31 output row in region
    const int c1  = (tid & 7) * 4;    // 0..28 output col base
    float acc[NL1][4];
    #pragma unroll
    for (int ch = 0; ch < NL1; ++ch)
        #pragma unroll
        for (int k = 0; k < 4; ++k) acc[ch][k] = 0.f;

    #pragma unroll
    for (int e = 0; e < KK; ++e) {
        float f0[12], f1[12], f2[12];
        LDX12(f0, 0, row + e, c1)
        LDX12(f1, 1, row + e, c1)
        LDX12(f2, 2, row + e, c1)
        #pragma unroll
        for (int ch = 0; ch < NL1; ++ch)
            #pragma unroll
            for (int dq = 0; dq < KK; ++dq) {
                const float wa = w1[ch * 147 +      e * 7 + dq];   // c=0
                const float wb = w1[ch * 147 + 49 + e * 7 + dq];   // c=1
                const float wc = w1[ch * 147 + 98 + e * 7 + dq];   // c=2
                #pragma unroll
                for (int k = 0; k < 4; ++k) {
                    acc[ch][k] = __builtin_fmaf(f0[dq + k], wa, acc[ch][k]);
                    acc[ch][k] = __builtin_fmaf(f1[dq + k], wb, acc[ch][k]);
                    acc[ch][k] = __builtin_fmaf(f2[dq + k], wc, acc[ch][k]);
                }
            }
    }
    // ---- store: every pixel in-image, computed exactly once ----
    const int gr = P0 + row, gc = Q0 + c1;
    #pragma unroll
    for (int ch = 0; ch < NL1; ++ch) {
        float4 st;
        st.x = acc[ch][0]; st.y = acc[ch][1]; st.z = acc[ch][2]; st.w = acc[ch][3];
        *(float4*)&o1g[(((size_t)n * NL1 + ch) * IMG + gr) * IMG + gc] = st;
    }
}

// =================== K2: conv2 + heaviside + histogram ===================
__global__ __launch_bounds__(256, 8) void pcanet_conv2(
    const float* __restrict__ o1g,  // (32,8,128,128) workspace
    const float* __restrict__ w2,   // (8,1,7,7)
    float* __restrict__ out)        // (32, 8*256*64)
{
    const int tid = threadIdx.x;
    const int reg = blockIdx.x;
    const int ch  = blockIdx.y;
    const int n   = blockIdx.z;
    const int P0  = (reg >> 2) * REG;
    const int Q0  = (reg & 3) * REG;

    __shared__ __align__(16) float o1[RT][O1P];      // 6.1KB
    __shared__ unsigned int hist[NHB * 32];          // 2KB

    const float* __restrict__ w2g = w2;              // wave-uniform -> s_load

    // ---- o1 tile fill (halo 3, zero-pad outside image) ----
    {
        const int lane = tid & 63, wv = tid >> 6;
        const float* src = o1g + ((size_t)n * NL1 + ch) * IMG * IMG;
        const int gc = Q0 - 3 + lane;
        const bool cok = (gc >= 0 && gc < IMG);
        if (lane < O1P) {
            for (int r = wv; r < RT; r += 4) {
                int gr = P0 - 3 + r;
                float v = 0.f;
                if (cok && gr >= 0 && gr < IMG)
                    v = src[(size_t)gr * IMG + gc];
                o1[r][lane] = v;
            }
        }
    }
    for (int i = tid; i < NHB * 32; i += 256) hist[i] = 0u;
    __syncthreads();

    // ---- conv2: thread owns 4 adjacent pixels (r, c0..c0+3) ----
    {
        const int r  = tid >> 3;
        const int c0 = (tid & 7) * 4;
        float acc[NL2][4];
        #pragma unroll
        for (int l = 0; l < NL2; ++l)
            #pragma unroll
            for (int k = 0; k < 4; ++k) acc[l][k] = 0.f;

        for (int dp = 0; dp < KK; ++dp) {
            float f[12];
            { float4 t_;
              t_ = *(const float4*)&o1[r + dp][c0];
              f[0]=t_.x; f[1]=t_.y; f[2]=t_.z; f[3]=t_.w;
              t_ = *(const float4*)&o1[r + dp][c0 + 4];
              f[4]=t_.x; f[5]=t_.y; f[6]=t_.z; f[7]=t_.w;
              t_ = *(const float4*)&o1[r + dp][c0 + 8];
              f[8]=t_.x; f[9]=t_.y; f[10]=t_.z; f[11]=t_.w; }
            #pragma unroll
            for (int l = 0; l < NL2; ++l)
                #pragma unroll
                for (int dq = 0; dq < KK; ++dq) {
                    float w = w2g[l * 49 + dp * 7 + dq];
                    acc[l][0] = __builtin_fmaf(f[dq + 0], w, acc[l][0]);
                    acc[l][1] = __builtin_fmaf(f[dq + 1], w, acc[l][1]);
                    acc[l][2] = __builtin_fmaf(f[dq + 2], w, acc[l][2]);
                    acc[l][3] = __builtin_fmaf(f[dq + 3], w, acc[l][3]);
                }
        }
        #pragma unroll
        for (int k = 0; k < 4; ++k) {
            int code = 0;
            #pragma unroll
            for (int l = 0; l < NL2; ++l)
                if (acc[l][k] > 0.0f) code |= (1 << l);
            int bin = code >> 2;
            int bc = (c0 + k) >> 3, br = r >> 3;
            atomicAdd(&hist[(br * 4 + bc) * 32 + (bin >> 1)],
                      1u << (16 * (bin & 1)));
        }
    }
    __syncthreads();

    // ---- write out 16 blocks x 64 bins (unpack halfwords) ----
    size_t planeBase = ((size_t)(n * NL1 + ch)) * 256 * NBINS;
    for (int i = tid; i < NHB * NBINS; i += 256) {
        int bl = i >> 6, bin = i & 63;
        unsigned int w = hist[bl * 32 + (bin >> 1)];
        unsigned int cnt = (w >> (16 * (bin & 1))) & 0xFFFFu;
        int br = bl >> 2, bc = bl & 3;
        int blkg = ((P0 >> 3) + br) * 16 + ((Q0 >> 3) + bc);
        out[planeBase + (size_t)blkg * NBINS + bin] = (float)cnt;
    }
}

// =================== Fallback: round-11 fused kernel (82us) ===================
#define C1TAPS(acc0, acc1, acc2, acc3, dp)                                   \
    _Pragma("unroll")                                                        \
    for (int dq = 0; dq < KK; ++dq) {                                        \
        float wa = w1g[(dp) * 7 + dq];                                       \
        float wb = w1g[49 + (dp) * 7 + dq];                                  \
        float wc = w1g[98 + (dp) * 7 + dq];                                  \
        acc0 = __builtin_fmaf(fx0[dq + 0], wa, acc0);                        \
        acc0 = __builtin_fmaf(fx1[dq + 0], wb, acc0);                        \
        acc0 = __builtin_fmaf(fx2[dq + 0], wc, acc0);                        \
        acc1 = __builtin_fmaf(fx0[dq + 1], wa, acc1);                        \
        acc1 = __builtin_fmaf(fx1[dq + 1], wb, acc1);                        \
        acc1 = __builtin_fmaf(fx2[dq + 1], wc, acc1);                        \
        acc2 = __builtin_fmaf(fx0[dq + 2], wa, acc2);                        \
        acc2 = __builtin_fmaf(fx1[dq + 2], wb, acc2);                        \
        acc2 = __builtin_fmaf(fx2[dq + 2], wc, acc2);                        \
        acc3 = __builtin_fmaf(fx0[dq + 3], wa, acc3);                        \
        acc3 = __builtin_fmaf(fx1[dq + 3], wb, acc3);                        \
        acc3 = __builtin_fmaf(fx2[dq + 3], wc, acc3);                        \
    }

#define LDXF(dst, plane, rw, col)                                            \
    { float4 t_;                                                             \
      t_ = *(const float4*)&xt[plane][rw][col];                              \
      dst[0]=t_.x; dst[1]=t_.y; dst[2]=t_.z; dst[3]=t_.w;                    \
      t_ = *(const float4*)&xt[plane][rw][(col)+4];                          \
      dst[4]=t_.x; dst[5]=t_.y; dst[6]=t_.z; dst[7]=t_.w;                    \
      t_ = *(const float4*)&xt[plane][rw][(col)+8];                          \
      dst[8]=t_.x; dst[9]=t_.y; dst[10]=t_.z; dst[11]=t_.w; }

__global__ __launch_bounds__(256, 5) void pcanet_fused(
    const float* __restrict__ x, const float* __restrict__ w1,
    const float* __restrict__ w2, float* __restrict__ out)
{
    const int tid = threadIdx.x;
    const int reg = blockIdx.x;
    const int ch  = blockIdx.y;
    const int n   = blockIdx.z;
    const int P0  = (reg >> 2) * REG;
    const int Q0  = (reg & 3) * REG;

    __shared__ __align__(16) float xt[3][XR][XTP];
    __shared__ __align__(16) float o1[RT][O1P];
    __shared__ unsigned int hist[NHB * 32];

    const float* __restrict__ w1g = w1 + ch * 147;
    const float* __restrict__ w2g = w2;

    {
        const int lane = tid & 63, wv = tid >> 6;
        const float* xn = x + (size_t)n * 3 * IMG * IMG;
        const int gs = Q0 - 6 + lane;
        const bool cok = (gs >= 0) && (gs < IMG);
        if (lane < XTP) {
            for (int c = 0; c < 3; ++c)
                for (int r = wv; r < XR; r += 4) {
                    int gr = P0 - 6 + r;
                    float v = 0.0f;
                    if (cok && gr >= 0 && gr < IMG)
                        v = xn[((size_t)c * IMG + gr) * IMG + gs];
                    xt[c][r][lane] = v;
                }
        }
    }
    for (int i = tid; i < NHB * 32; i += 256) hist[i] = 0u;
    __syncthreads();

    if (tid < 190) {
        int pr = tid / 10, c1 = 4 * (tid % 10), r0 = 2 * pr;
        float a0 = 0.f, a1 = 0.f, a2 = 0.f, a3 = 0.f;
        float b0 = 0.f, b1 = 0.f, b2 = 0.f, b3 = 0.f;
        #pragma unroll
        for (int e = 0; e < 8; ++e) {
            float fx0[12], fx1[12], fx2[12];
            LDXF(fx0, 0, r0 + e, c1)
            LDXF(fx1, 1, r0 + e, c1)
            LDXF(fx2, 2, r0 + e, c1)
            if (e < 7)  { C1TAPS(a0, a1, a2, a3, e) }
            if (e >= 1) { C1TAPS(b0, b1, b2, b3, e - 1) }
        }
        int gs0 = Q0 - 3 + c1;
        bool c0ok = (gs0 + 0 >= 0 && gs0 + 0 < IMG);
        bool c1ok = (gs0 + 1 >= 0 && gs0 + 1 < IMG);
        bool c2ok = (gs0 + 2 >= 0 && gs0 + 2 < IMG);
        bool c3ok = (gs0 + 3 >= 0 && gs0 + 3 < IMG);
        {
            int gr = P0 - 3 + r0;
            bool rok = (gr >= 0 && gr < IMG);
            float4 st;
            st.x = (rok && c0ok) ? a0 : 0.f; st.y = (rok && c1ok) ? a1 : 0.f;
            st.z = (rok && c2ok) ? a2 : 0.f; st.w = (rok && c3ok) ? a3 : 0.f;
            *(float4*)&o1[r0][c1] = st;
        }
        {
            int gr = P0 - 3 + r0 + 1;
            bool rok = (gr >= 0 && gr < IMG);
            float4 st;
            st.x = (rok && c0ok) ? b0 : 0.f; st.y = (rok && c1ok) ? b1 : 0.f;
            st.z = (rok && c2ok) ? b2 : 0.f; st.w = (rok && c3ok) ? b3 : 0.f;
            *(float4*)&o1[r0 + 1][c1] = st;
        }
    }
    __syncthreads();

    {
        const int r  = tid >> 3;
        const int c0 = (tid & 7) * 4;
        float acc[NL2][4];
        #pragma unroll
        for (int l = 0; l < NL2; ++l)
            #pragma unroll
            for (int k = 0; k < 4; ++k) acc[l][k] = 0.f;

        for (int dp = 0; dp < KK; ++dp) {
            float f[12];
            { float4 t_;
              t_ = *(const float4*)&o1[r + dp][c0];
              f[0]=t_.x; f[1]=t_.y; f[2]=t_.z; f[3]=t_.w;
              t_ = *(const float4*)&o1[r + dp][c0 + 4];
              f[4]=t_.x; f[5]=t_.y; f[6]=t_.z; f[7]=t_.w;
              t_ = *(const float4*)&o1[r + dp][c0 + 8];
              f[8]=t_.x; f[9]=t_.y; f[10]=t_.z; f[11]=t_.w; }
            #pragma unroll
            for (int l = 0; l < NL2; ++l)
                #pragma unroll
                for (int dq = 0; dq < KK; ++dq) {
                    float w = w2g[l * 49 + dp * 7 + dq];
                    acc[l][0] = __builtin_fmaf(f[dq + 0], w, acc[l][0]);
                    acc[l][1] = __builtin_fmaf(f[dq + 1], w, acc[l][1]);
                    acc[l][2] = __builtin_fmaf(f[dq + 2], w, acc[l][2]);
                    acc[l][3] = __builtin_fmaf(f[dq + 3], w, acc[l][3]);
                }
        }
        #pragma unroll
        for (int k = 0; k < 4; ++k) {
            int code = 0;
            #pragma unroll
            for (int l = 0; l < NL2; ++l)
                if (acc[l][k] > 0.0f) code |= (1 << l);
            int bin = code >> 2;
            int bc = (c0 + k) >> 3, br = r >> 3;
            atomicAdd(&hist[(br * 4 + bc) * 32 + (bin >> 1)],
                      1u << (16 * (bin & 1)));
        }
    }
    __syncthreads();

    size_t planeBase = ((size_t)(n * NL1 + ch)) * 256 * NBINS;
    for (int i = tid; i < NHB * NBINS; i += 256) {
        int bl = i >> 6, bin = i & 63;
        unsigned int w = hist[bl * 32 + (bin >> 1)];
        unsigned int cnt = (w >> (16 * (bin & 1))) & 0xFFFFu;
        int br = bl >> 2, bc = bl & 3;
        int blkg = ((P0 >> 3) + br) * 16 + ((Q0 >> 3) + bc);
        out[planeBase + (size_t)blkg * NBINS + bin] = (float)cnt;
    }
}

extern "C" void kernel_launch(void* const* d_in, const int* in_sizes, int n_in,
                              void* d_out, int out_size, void* d_ws, size_t ws_size,
                              hipStream_t stream) {
    const float* x  = (const float*)d_in[0];
    const float* w1 = (const float*)d_in[1];
    const float* w2 = (const float*)d_in[2];
    float* out = (float*)d_out;

    const size_t need = (size_t)32 * NL1 * IMG * IMG * sizeof(float);  // 16.8MB
    if (ws_size >= need) {
        float* o1g = (float*)d_ws;
        pcanet_conv1<<<dim3(16, 32),      256, 0, stream>>>(x, w1, o1g);
        pcanet_conv2<<<dim3(16, NL1, 32), 256, 0, stream>>>(o1g, w2, out);
    } else {
        pcanet_fused<<<dim3(16, NL1, 32), 256, 0, stream>>>(x, w1, w2, out);
    }
}

// Round 18
// 98.327 us; speedup vs baseline: 2.7668x; 2.7668x over previous
//
#include <hip/hip_runtime.h>
#include <hip/hip_bf16.h>

#define KK 7
#define NL1 8
#define NL2 8
#define IMG 128
#define REG 32            // region edge (pixels) per workgroup
#define RT 38             // tile edge = REG + 6
#define O1P 40            // tile pitch (160B, 16B-aligned)
#define XR 44             // fused-kernel xt real rows/cols
#define XTP 44            // fused-kernel xt pitch
#define NBINS 64
#define NHB 16            // histogram blocks per region (4x4 of 8x8)

// Correctness contract (matches XLA-CPU f32 reference, verified round 6):
//  conv1: per-pixel strict sequential FMA chain, taps ordered dp->dq->c(fastest)
//  out1 : materialized as f32 (and zeroed outside the image = conv2 padding)
//  conv2: per-filter strict sequential FMA chain, taps ordered dp->dq
// Restructuring only changes WHERE operands come from, never per-chain order.
//
// Round-18: K1 was grid-starved (512 wgs = 2 blocks/CU, occupancy 23%,
// 230us). Split K1 by channel-pairs: grid (16 regions x 4 chpairs x 32 img)
// = 2048 wgs = 8 blocks/CU; each thread 2ch x 4px (8 accs), same shared
// window reads (FMA:ds_read ~19:1). launch_bounds(256,8) caps VGPR at 64.
// K2 unchanged. Fallback: round-11 fused kernel if ws too small.

#define LDX12(dst, plane, row, col)                                          \
    { float4 t_;                                                             \
      t_ = *(const float4*)&xt[plane][row][col];                             \
      dst[0]=t_.x; dst[1]=t_.y; dst[2]=t_.z; dst[3]=t_.w;                    \
      t_ = *(const float4*)&xt[plane][row][(col)+4];                         \
      dst[4]=t_.x; dst[5]=t_.y; dst[6]=t_.z; dst[7]=t_.w;                    \
      t_ = *(const float4*)&xt[plane][row][(col)+8];                         \
      dst[8]=t_.x; dst[9]=t_.y; dst[10]=t_.z; dst[11]=t_.w; }

// =================== K1: conv1, exactly-once, 2-ch per wg ===================
__global__ __launch_bounds__(256, 8) void pcanet_conv1(
    const float* __restrict__ x,    // (32,3,128,128)
    const float* __restrict__ w1,   // (8,3,7,7)
    float* __restrict__ o1g)        // (32,8,128,128) workspace
{
    const int tid = threadIdx.x;        // 0..255
    const int reg = blockIdx.x;         // 0..15 : 4x4 regions
    const int ch0 = blockIdx.y * 2;     // channel pair base: 0,2,4,6
    const int n   = blockIdx.z;         // image index
    const int P0  = (reg >> 2) * REG;
    const int Q0  = (reg & 3) * REG;

    __shared__ __align__(16) float xt[3][RT][O1P];   // 3x38x40 = 18.2KB

    // ---- x tile fill (halo 3): lane = col, rows wave-strided ----
    {
        const int lane = tid & 63, wv = tid >> 6;
        const float* xn = x + (size_t)n * 3 * IMG * IMG;
        const int gc = Q0 - 3 + lane;
        const bool cok = (gc >= 0 && gc < IMG);
        if (lane < O1P) {
            for (int c = 0; c < 3; ++c)
                for (int r = wv; r < RT; r += 4) {
                    int gr = P0 - 3 + r;
                    float v = 0.f;
                    if (cok && gr >= 0 && gr < IMG)
                        v = xn[((size_t)c * IMG + gr) * IMG + gc];
                    xt[c][r][lane] = v;
                }
        }
    }
    __syncthreads();

    // ---- conv1: thread owns (row, c1..c1+3) for channels ch0, ch0+1 ----
    const int row = tid >> 3;         // 0..31 output row in region
    const int c1  = (tid & 7) * 4;    // 0..28 output col base
    float acc[2][4];
    #pragma unroll
    for (int ch = 0; ch < 2; ++ch)
        #pragma unroll
        for (int k = 0; k < 4; ++k) acc[ch][k] = 0.f;

    #pragma unroll
    for (int e = 0; e < KK; ++e) {
        float f0[12], f1[12], f2[12];
        LDX12(f0, 0, row + e, c1)
        LDX12(f1, 1, row + e, c1)
        LDX12(f2, 2, row + e, c1)
        #pragma unroll
        for (int ch = 0; ch < 2; ++ch) {
            const float* wch = w1 + (ch0 + ch) * 147;
            #pragma unroll
            for (int dq = 0; dq < KK; ++dq) {
                const float wa = wch[     e * 7 + dq];   // c=0
                const float wb = wch[49 + e * 7 + dq];   // c=1
                const float wc = wch[98 + e * 7 + dq];   // c=2
                #pragma unroll
                for (int k = 0; k < 4; ++k) {
                    acc[ch][k] = __builtin_fmaf(f0[dq + k], wa, acc[ch][k]);
                    acc[ch][k] = __builtin_fmaf(f1[dq + k], wb, acc[ch][k]);
                    acc[ch][k] = __builtin_fmaf(f2[dq + k], wc, acc[ch][k]);
                }
            }
        }
    }
    // ---- store: every pixel in-image, computed exactly once ----
    const int gr = P0 + row, gc = Q0 + c1;
    #pragma unroll
    for (int ch = 0; ch < 2; ++ch) {
        float4 st;
        st.x = acc[ch][0]; st.y = acc[ch][1]; st.z = acc[ch][2]; st.w = acc[ch][3];
        *(float4*)&o1g[(((size_t)n * NL1 + ch0 + ch) * IMG + gr) * IMG + gc] = st;
    }
}

// =================== K2: conv2 + heaviside + histogram ===================
__global__ __launch_bounds__(256, 8) void pcanet_conv2(
    const float* __restrict__ o1g,  // (32,8,128,128) workspace
    const float* __restrict__ w2,   // (8,1,7,7)
    float* __restrict__ out)        // (32, 8*256*64)
{
    const int tid = threadIdx.x;
    const int reg = blockIdx.x;
    const int ch  = blockIdx.y;
    const int n   = blockIdx.z;
    const int P0  = (reg >> 2) * REG;
    const int Q0  = (reg & 3) * REG;

    __shared__ __align__(16) float o1[RT][O1P];      // 6.1KB
    __shared__ unsigned int hist[NHB * 32];          // 2KB

    const float* __restrict__ w2g = w2;              // wave-uniform -> s_load

    // ---- o1 tile fill (halo 3, zero-pad outside image) ----
    {
        const int lane = tid & 63, wv = tid >> 6;
        const float* src = o1g + ((size_t)n * NL1 + ch) * IMG * IMG;
        const int gc = Q0 - 3 + lane;
        const bool cok = (gc >= 0 && gc < IMG);
        if (lane < O1P) {
            for (int r = wv; r < RT; r += 4) {
                int gr = P0 - 3 + r;
                float v = 0.f;
                if (cok && gr >= 0 && gr < IMG)
                    v = src[(size_t)gr * IMG + gc];
                o1[r][lane] = v;
            }
        }
    }
    for (int i = tid; i < NHB * 32; i += 256) hist[i] = 0u;
    __syncthreads();

    // ---- conv2: thread owns 4 adjacent pixels (r, c0..c0+3) ----
    {
        const int r  = tid >> 3;
        const int c0 = (tid & 7) * 4;
        float acc[NL2][4];
        #pragma unroll
        for (int l = 0; l < NL2; ++l)
            #pragma unroll
            for (int k = 0; k < 4; ++k) acc[l][k] = 0.f;

        for (int dp = 0; dp < KK; ++dp) {
            float f[12];
            { float4 t_;
              t_ = *(const float4*)&o1[r + dp][c0];
              f[0]=t_.x; f[1]=t_.y; f[2]=t_.z; f[3]=t_.w;
              t_ = *(const float4*)&o1[r + dp][c0 + 4];
              f[4]=t_.x; f[5]=t_.y; f[6]=t_.z; f[7]=t_.w;
              t_ = *(const float4*)&o1[r + dp][c0 + 8];
              f[8]=t_.x; f[9]=t_.y; f[10]=t_.z; f[11]=t_.w; }
            #pragma unroll
            for (int l = 0; l < NL2; ++l)
                #pragma unroll
                for (int dq = 0; dq < KK; ++dq) {
                    float w = w2g[l * 49 + dp * 7 + dq];
                    acc[l][0] = __builtin_fmaf(f[dq + 0], w, acc[l][0]);
                    acc[l][1] = __builtin_fmaf(f[dq + 1], w, acc[l][1]);
                    acc[l][2] = __builtin_fmaf(f[dq + 2], w, acc[l][2]);
                    acc[l][3] = __builtin_fmaf(f[dq + 3], w, acc[l][3]);
                }
        }
        #pragma unroll
        for (int k = 0; k < 4; ++k) {
            int code = 0;
            #pragma unroll
            for (int l = 0; l < NL2; ++l)
                if (acc[l][k] > 0.0f) code |= (1 << l);
            int bin = code >> 2;
            int bc = (c0 + k) >> 3, br = r >> 3;
            atomicAdd(&hist[(br * 4 + bc) * 32 + (bin >> 1)],
                      1u << (16 * (bin & 1)));
        }
    }
    __syncthreads();

    // ---- write out 16 blocks x 64 bins (unpack halfwords) ----
    size_t planeBase = ((size_t)(n * NL1 + ch)) * 256 * NBINS;
    for (int i = tid; i < NHB * NBINS; i += 256) {
        int bl = i >> 6, bin = i & 63;
        unsigned int w = hist[bl * 32 + (bin >> 1)];
        unsigned int cnt = (w >> (16 * (bin & 1))) & 0xFFFFu;
        int br = bl >> 2, bc = bl & 3;
        int blkg = ((P0 >> 3) + br) * 16 + ((Q0 >> 3) + bc);
        out[planeBase + (size_t)blkg * NBINS + bin] = (float)cnt;
    }
}

// =================== Fallback: round-11 fused kernel (82us) ===================
#define C1TAPS(acc0, acc1, acc2, acc3, dp)                                   \
    _Pragma("unroll")                                                        \
    for (int dq = 0; dq < KK; ++dq) {                                        \
        float wa = w1g[(dp) * 7 + dq];                                       \
        float wb = w1g[49 + (dp) * 7 + dq];                                  \
        float wc = w1g[98 + (dp) * 7 + dq];                                  \
        acc0 = __builtin_fmaf(fx0[dq + 0], wa, acc0);                        \
        acc0 = __builtin_fmaf(fx1[dq + 0], wb, acc0);                        \
        acc0 = __builtin_fmaf(fx2[dq + 0], wc, acc0);                        \
        acc1 = __builtin_fmaf(fx0[dq + 1], wa, acc1);                        \
        acc1 = __builtin_fmaf(fx1[dq + 1], wb, acc1);                        \
        acc1 = __builtin_fmaf(fx2[dq + 1], wc, acc1);                        \
        acc2 = __builtin_fmaf(fx0[dq + 2], wa, acc2);                        \
        acc2 = __builtin_fmaf(fx1[dq + 2], wb, acc2);                        \
        acc2 = __builtin_fmaf(fx2[dq + 2], wc, acc2);                        \
        acc3 = __builtin_fmaf(fx0[dq + 3], wa, acc3);                        \
        acc3 = __builtin_fmaf(fx1[dq + 3], wb, acc3);                        \
        acc3 = __builtin_fmaf(fx2[dq + 3], wc, acc3);                        \
    }

#define LDXF(dst, plane, rw, col)                                            \
    { float4 t_;                                                             \
      t_ = *(const float4*)&xt[plane][rw][col];                              \
      dst[0]=t_.x; dst[1]=t_.y; dst[2]=t_.z; dst[3]=t_.w;                    \
      t_ = *(const float4*)&xt[plane][rw][(col)+4];                          \
      dst[4]=t_.x; dst[5]=t_.y; dst[6]=t_.z; dst[7]=t_.w;                    \
      t_ = *(const float4*)&xt[plane][rw][(col)+8];                          \
      dst[8]=t_.x; dst[9]=t_.y; dst[10]=t_.z; dst[11]=t_.w; }

__global__ __launch_bounds__(256, 5) void pcanet_fused(
    const float* __restrict__ x, const float* __restrict__ w1,
    const float* __restrict__ w2, float* __restrict__ out)
{
    const int tid = threadIdx.x;
    const int reg = blockIdx.x;
    const int ch  = blockIdx.y;
    const int n   = blockIdx.z;
    const int P0  = (reg >> 2) * REG;
    const int Q0  = (reg & 3) * REG;

    __shared__ __align__(16) float xt[3][XR][XTP];
    __shared__ __align__(16) float o1[RT][O1P];
    __shared__ unsigned int hist[NHB * 32];

    const float* __restrict__ w1g = w1 + ch * 147;
    const float* __restrict__ w2g = w2;

    {
        const int lane = tid & 63, wv = tid >> 6;
        const float* xn = x + (size_t)n * 3 * IMG * IMG;
        const int gs = Q0 - 6 + lane;
        const bool cok = (gs >= 0) && (gs < IMG);
        if (lane < XTP) {
            for (int c = 0; c < 3; ++c)
                for (int r = wv; r < XR; r += 4) {
                    int gr = P0 - 6 + r;
                    float v = 0.0f;
                    if (cok && gr >= 0 && gr < IMG)
                        v = xn[((size_t)c * IMG + gr) * IMG + gs];
                    xt[c][r][lane] = v;
                }
        }
    }
    for (int i = tid; i < NHB * 32; i += 256) hist[i] = 0u;
    __syncthreads();

    if (tid < 190) {
        int pr = tid / 10, c1 = 4 * (tid % 10), r0 = 2 * pr;
        float a0 = 0.f, a1 = 0.f, a2 = 0.f, a3 = 0.f;
        float b0 = 0.f, b1 = 0.f, b2 = 0.f, b3 = 0.f;
        #pragma unroll
        for (int e = 0; e < 8; ++e) {
            float fx0[12], fx1[12], fx2[12];
            LDXF(fx0, 0, r0 + e, c1)
            LDXF(fx1, 1, r0 + e, c1)
            LDXF(fx2, 2, r0 + e, c1)
            if (e < 7)  { C1TAPS(a0, a1, a2, a3, e) }
            if (e >= 1) { C1TAPS(b0, b1, b2, b3, e - 1) }
        }
        int gs0 = Q0 - 3 + c1;
        bool c0ok = (gs0 + 0 >= 0 && gs0 + 0 < IMG);
        bool c1ok = (gs0 + 1 >= 0 && gs0 + 1 < IMG);
        bool c2ok = (gs0 + 2 >= 0 && gs0 + 2 < IMG);
        bool c3ok = (gs0 + 3 >= 0 && gs0 + 3 < IMG);
        {
            int gr = P0 - 3 + r0;
            bool rok = (gr >= 0 && gr < IMG);
            float4 st;
            st.x = (rok && c0ok) ? a0 : 0.f; st.y = (rok && c1ok) ? a1 : 0.f;
            st.z = (rok && c2ok) ? a2 : 0.f; st.w = (rok && c3ok) ? a3 : 0.f;
            *(float4*)&o1[r0][c1] = st;
        }
        {
            int gr = P0 - 3 + r0 + 1;
            bool rok = (gr >= 0 && gr < IMG);
            float4 st;
            st.x = (rok && c0ok) ? b0 : 0.f; st.y = (rok && c1ok) ? b1 : 0.f;
            st.z = (rok && c2ok) ? b2 : 0.f; st.w = (rok && c3ok) ? b3 : 0.f;
            *(float4*)&o1[r0 + 1][c1] = st;
        }
    }
    __syncthreads();

    {
        const int r  = tid >> 3;
        const int c0 = (tid & 7) * 4;
        float acc[NL2][4];
        #pragma unroll
        for (int l = 0; l < NL2; ++l)
            #pragma unroll
            for (int k = 0; k < 4; ++k) acc[l][k] = 0.f;

        for (int dp = 0; dp < KK; ++dp) {
            float f[12];
            { float4 t_;
              t_ = *(const float4*)&o1[r + dp][c0];
              f[0]=t_.x; f[1]=t_.y; f[2]=t_.z; f[3]=t_.w;
              t_ = *(const float4*)&o1[r + dp][c0 + 4];
              f[4]=t_.x; f[5]=t_.y; f[6]=t_.z; f[7]=t_.w;
              t_ = *(const float4*)&o1[r + dp][c0 + 8];
              f[8]=t_.x; f[9]=t_.y; f[10]=t_.z; f[11]=t_.w; }
            #pragma unroll
            for (int l = 0; l < NL2; ++l)
                #pragma unroll
                for (int dq = 0; dq < KK; ++dq) {
                    float w = w2g[l * 49 + dp * 7 + dq];
                    acc[l][0] = __builtin_fmaf(f[dq + 0], w, acc[l][0]);
                    acc[l][1] = __builtin_fmaf(f[dq + 1], w, acc[l][1]);
                    acc[l][2] = __builtin_fmaf(f[dq + 2], w, acc[l][2]);
                    acc[l][3] = __builtin_fmaf(f[dq + 3], w, acc[l][3]);
                }
        }
        #pragma unroll
        for (int k = 0; k < 4; ++k) {
            int code = 0;
            #pragma unroll
            for (int l = 0; l < NL2; ++l)
                if (acc[l][k] > 0.0f) code |= (1 << l);
            int bin = code >> 2;
            int bc = (c0 + k) >> 3, br = r >> 3;
            atomicAdd(&hist[(br * 4 + bc) * 32 + (bin >> 1)],
                      1u << (16 * (bin & 1)));
        }
    }
    __syncthreads();

    size_t planeBase = ((size_t)(n * NL1 + ch)) * 256 * NBINS;
    for (int i = tid; i < NHB * NBINS; i += 256) {
        int bl = i >> 6, bin = i & 63;
        unsigned int w = hist[bl * 32 + (bin >> 1)];
        unsigned int cnt = (w >> (16 * (bin & 1))) & 0xFFFFu;
        int br = bl >> 2, bc = bl & 3;
        int blkg = ((P0 >> 3) + br) * 16 + ((Q0 >> 3) + bc);
        out[planeBase + (size_t)blkg * NBINS + bin] = (float)cnt;
    }
}

extern "C" void kernel_launch(void* const* d_in, const int* in_sizes, int n_in,
                              void* d_out, int out_size, void* d_ws, size_t ws_size,
                              hipStream_t stream) {
    const float* x  = (const float*)d_in[0];
    const float* w1 = (const float*)d_in[1];
    const float* w2 = (const float*)d_in[2];
    float* out = (float*)d_out;

    const size_t need = (size_t)32 * NL1 * IMG * IMG * sizeof(float);  // 16.8MB
    if (ws_size >= need) {
        float* o1g = (float*)d_ws;
        pcanet_conv1<<<dim3(16, 4, 32),   256, 0, stream>>>(x, w1, o1g);
        pcanet_conv2<<<dim3(16, NL1, 32), 256, 0, stream>>>(o1g, w2, out);
    } else {
        pcanet_fused<<<dim3(16, NL1, 32), 256, 0, stream>>>(x, w1, w2, out);
    }
}

// Round 19
// 93.813 us; speedup vs baseline: 2.8999x; 1.0481x over previous
//
#include <hip/hip_runtime.h>
#include <hip/hip_bf16.h>

#define KK 7
#define NL1 8
#define NL2 8
#define IMG 128
#define REG 32            // region edge (pixels) per workgroup
#define RT 38             // tile edge = REG + 6
#define O1P 40            // tile pitch (160B, 16B-aligned)
#define XR 44             // fused-kernel xt real rows/cols
#define XTP 44            // fused-kernel xt pitch
#define NBINS 64
#define NHB 16            // histogram blocks per region (4x4 of 8x8)

// Correctness contract (matches XLA-CPU f32 reference, verified round 6):
//  conv1: per-pixel strict sequential FMA chain, taps ordered dp->dq->c(fastest)
//  out1 : materialized as f32 (and zeroed outside the image = conv2 padding)
//  conv2: per-filter strict sequential FMA chain, taps ordered dp->dq
// Restructuring only changes WHERE operands come from, never per-chain order.
//
// Round-19: K2's VGPR_Count=32 proved the compiler rematerialized the o1 LDS
// reads per-filter (acc[8][4]+f[12] needs >=44 regs, cap was 64) -> ~8x the
// intended ds_read traffic. Now conv2 runs as TWO explicit filter-group
// passes (l=0..3 then l=4..7), 16 NAMED accumulators each (~40 VGPR), with
// sched_barrier(0) between passes so they can't be merged. LDS reads/thread
// 168 -> 42. Sign bits accumulate into per-pixel code ints across passes.

#define LDX12(dst, plane, row, col)                                          \
    { float4 t_;                                                             \
      t_ = *(const float4*)&xt[plane][row][col];                             \
      dst[0]=t_.x; dst[1]=t_.y; dst[2]=t_.z; dst[3]=t_.w;                    \
      t_ = *(const float4*)&xt[plane][row][(col)+4];                         \
      dst[4]=t_.x; dst[5]=t_.y; dst[6]=t_.z; dst[7]=t_.w;                    \
      t_ = *(const float4*)&xt[plane][row][(col)+8];                         \
      dst[8]=t_.x; dst[9]=t_.y; dst[10]=t_.z; dst[11]=t_.w; }

// =================== K1: conv1, exactly-once, 2-ch per wg ===================
__global__ __launch_bounds__(256, 8) void pcanet_conv1(
    const float* __restrict__ x,    // (32,3,128,128)
    const float* __restrict__ w1,   // (8,3,7,7)
    float* __restrict__ o1g)        // (32,8,128,128) workspace
{
    const int tid = threadIdx.x;        // 0..255
    const int reg = blockIdx.x;         // 0..15 : 4x4 regions
    const int ch0 = blockIdx.y * 2;     // channel pair base: 0,2,4,6
    const int n   = blockIdx.z;         // image index
    const int P0  = (reg >> 2) * REG;
    const int Q0  = (reg & 3) * REG;

    __shared__ __align__(16) float xt[3][RT][O1P];   // 3x38x40 = 18.2KB

    // ---- x tile fill (halo 3): lane = col, rows wave-strided ----
    {
        const int lane = tid & 63, wv = tid >> 6;
        const float* xn = x + (size_t)n * 3 * IMG * IMG;
        const int gc = Q0 - 3 + lane;
        const bool cok = (gc >= 0 && gc < IMG);
        if (lane < O1P) {
            for (int c = 0; c < 3; ++c)
                for (int r = wv; r < RT; r += 4) {
                    int gr = P0 - 3 + r;
                    float v = 0.f;
                    if (cok && gr >= 0 && gr < IMG)
                        v = xn[((size_t)c * IMG + gr) * IMG + gc];
                    xt[c][r][lane] = v;
                }
        }
    }
    __syncthreads();

    // ---- conv1: thread owns (row, c1..c1+3) for channels ch0, ch0+1 ----
    const int row = tid >> 3;         // 0..31 output row in region
    const int c1  = (tid & 7) * 4;    // 0..28 output col base
    float acc[2][4];
    #pragma unroll
    for (int ch = 0; ch < 2; ++ch)
        #pragma unroll
        for (int k = 0; k < 4; ++k) acc[ch][k] = 0.f;

    #pragma unroll
    for (int e = 0; e < KK; ++e) {
        float f0[12], f1[12], f2[12];
        LDX12(f0, 0, row + e, c1)
        LDX12(f1, 1, row + e, c1)
        LDX12(f2, 2, row + e, c1)
        #pragma unroll
        for (int ch = 0; ch < 2; ++ch) {
            const float* wch = w1 + (ch0 + ch) * 147;
            #pragma unroll
            for (int dq = 0; dq < KK; ++dq) {
                const float wa = wch[     e * 7 + dq];   // c=0
                const float wb = wch[49 + e * 7 + dq];   // c=1
                const float wc = wch[98 + e * 7 + dq];   // c=2
                #pragma unroll
                for (int k = 0; k < 4; ++k) {
                    acc[ch][k] = __builtin_fmaf(f0[dq + k], wa, acc[ch][k]);
                    acc[ch][k] = __builtin_fmaf(f1[dq + k], wb, acc[ch][k]);
                    acc[ch][k] = __builtin_fmaf(f2[dq + k], wc, acc[ch][k]);
                }
            }
        }
    }
    // ---- store: every pixel in-image, computed exactly once ----
    const int gr = P0 + row, gc = Q0 + c1;
    #pragma unroll
    for (int ch = 0; ch < 2; ++ch) {
        float4 st;
        st.x = acc[ch][0]; st.y = acc[ch][1]; st.z = acc[ch][2]; st.w = acc[ch][3];
        *(float4*)&o1g[(((size_t)n * NL1 + ch0 + ch) * IMG + gr) * IMG + gc] = st;
    }
}

// =================== K2: conv2 + heaviside + histogram ===================
// one filter-group pass: filters LBASE..LBASE+3, 16 named accumulators
#define C2PASS(LBASE)                                                        \
{                                                                            \
    float a00=0.f,a01=0.f,a02=0.f,a03=0.f;                                   \
    float a10=0.f,a11=0.f,a12=0.f,a13=0.f;                                   \
    float a20=0.f,a21=0.f,a22=0.f,a23=0.f;                                   \
    float a30=0.f,a31=0.f,a32=0.f,a33=0.f;                                   \
    for (int dp = 0; dp < KK; ++dp) {                                        \
        float f[12];                                                         \
        { float4 t_;                                                         \
          t_ = *(const float4*)&o1[r + dp][c0];                              \
          f[0]=t_.x; f[1]=t_.y; f[2]=t_.z; f[3]=t_.w;                        \
          t_ = *(const float4*)&o1[r + dp][c0 + 4];                          \
          f[4]=t_.x; f[5]=t_.y; f[6]=t_.z; f[7]=t_.w;                        \
          t_ = *(const float4*)&o1[r + dp][c0 + 8];                          \
          f[8]=t_.x; f[9]=t_.y; f[10]=t_.z; f[11]=t_.w; }                    \
        _Pragma("unroll")                                                    \
        for (int dq = 0; dq < KK; ++dq) {                                    \
            float w0 = w2g[(LBASE + 0) * 49 + dp * 7 + dq];                  \
            float w1_ = w2g[(LBASE + 1) * 49 + dp * 7 + dq];                 \
            float w2_ = w2g[(LBASE + 2) * 49 + dp * 7 + dq];                 \
            float w3_ = w2g[(LBASE + 3) * 49 + dp * 7 + dq];                 \
            a00 = __builtin_fmaf(f[dq + 0], w0,  a00);                       \
            a01 = __builtin_fmaf(f[dq + 1], w0,  a01);                       \
            a02 = __builtin_fmaf(f[dq + 2], w0,  a02);                       \
            a03 = __builtin_fmaf(f[dq + 3], w0,  a03);                       \
            a10 = __builtin_fmaf(f[dq + 0], w1_, a10);                       \
            a11 = __builtin_fmaf(f[dq + 1], w1_, a11);                       \
            a12 = __builtin_fmaf(f[dq + 2], w1_, a12);                       \
            a13 = __builtin_fmaf(f[dq + 3], w1_, a13);                       \
            a20 = __builtin_fmaf(f[dq + 0], w2_, a20);                       \
            a21 = __builtin_fmaf(f[dq + 1], w2_, a21);                       \
            a22 = __builtin_fmaf(f[dq + 2], w2_, a22);                       \
            a23 = __builtin_fmaf(f[dq + 3], w2_, a23);                       \
            a30 = __builtin_fmaf(f[dq + 0], w3_, a30);                       \
            a31 = __builtin_fmaf(f[dq + 1], w3_, a31);                       \
            a32 = __builtin_fmaf(f[dq + 2], w3_, a32);                       \
            a33 = __builtin_fmaf(f[dq + 3], w3_, a33);                       \
        }                                                                    \
    }                                                                        \
    if (a00 > 0.0f) code0 |= 1 << (LBASE + 0);                               \
    if (a01 > 0.0f) code1 |= 1 << (LBASE + 0);                               \
    if (a02 > 0.0f) code2 |= 1 << (LBASE + 0);                               \
    if (a03 > 0.0f) code3 |= 1 << (LBASE + 0);                               \
    if (a10 > 0.0f) code0 |= 1 << (LBASE + 1);                               \
    if (a11 > 0.0f) code1 |= 1 << (LBASE + 1);                               \
    if (a12 > 0.0f) code2 |= 1 << (LBASE + 1);                               \
    if (a13 > 0.0f) code3 |= 1 << (LBASE + 1);                               \
    if (a20 > 0.0f) code0 |= 1 << (LBASE + 2);                               \
    if (a21 > 0.0f) code1 |= 1 << (LBASE + 2);                               \
    if (a22 > 0.0f) code2 |= 1 << (LBASE + 2);                               \
    if (a23 > 0.0f) code3 |= 1 << (LBASE + 2);                               \
    if (a30 > 0.0f) code0 |= 1 << (LBASE + 3);                               \
    if (a31 > 0.0f) code1 |= 1 << (LBASE + 3);                               \
    if (a32 > 0.0f) code2 |= 1 << (LBASE + 3);                               \
    if (a33 > 0.0f) code3 |= 1 << (LBASE + 3);                               \
}

__global__ __launch_bounds__(256, 8) void pcanet_conv2(
    const float* __restrict__ o1g,  // (32,8,128,128) workspace
    const float* __restrict__ w2,   // (8,1,7,7)
    float* __restrict__ out)        // (32, 8*256*64)
{
    const int tid = threadIdx.x;
    const int reg = blockIdx.x;
    const int ch  = blockIdx.y;
    const int n   = blockIdx.z;
    const int P0  = (reg >> 2) * REG;
    const int Q0  = (reg & 3) * REG;

    __shared__ __align__(16) float o1[RT][O1P];      // 6.1KB
    __shared__ unsigned int hist[NHB * 32];          // 2KB

    const float* __restrict__ w2g = w2;              // wave-uniform -> s_load

    // ---- o1 tile fill (halo 3, zero-pad outside image) ----
    {
        const int lane = tid & 63, wv = tid >> 6;
        const float* src = o1g + ((size_t)n * NL1 + ch) * IMG * IMG;
        const int gc = Q0 - 3 + lane;
        const bool cok = (gc >= 0 && gc < IMG);
        if (lane < O1P) {
            for (int r = wv; r < RT; r += 4) {
                int gr = P0 - 3 + r;
                float v = 0.f;
                if (cok && gr >= 0 && gr < IMG)
                    v = src[(size_t)gr * IMG + gc];
                o1[r][lane] = v;
            }
        }
    }
    for (int i = tid; i < NHB * 32; i += 256) hist[i] = 0u;
    __syncthreads();

    // ---- conv2: thread owns 4 adjacent pixels; two filter-group passes ----
    {
        const int r  = tid >> 3;
        const int c0 = (tid & 7) * 4;
        int code0 = 0, code1 = 0, code2 = 0, code3 = 0;

        C2PASS(0)
        __builtin_amdgcn_sched_barrier(0);   // keep the passes separate
        C2PASS(4)

        const int br = r >> 3;
        const int bcb = c0 >> 3;             // block col of k=0..3 (c0 mod 8 in {0,4})
        int bin;
        bin = code0 >> 2;
        atomicAdd(&hist[(br * 4 + bcb) * 32 + (bin >> 1)], 1u << (16 * (bin & 1)));
        bin = code1 >> 2;
        atomicAdd(&hist[(br * 4 + ((c0 + 1) >> 3)) * 32 + (bin >> 1)], 1u << (16 * (bin & 1)));
        bin = code2 >> 2;
        atomicAdd(&hist[(br * 4 + ((c0 + 2) >> 3)) * 32 + (bin >> 1)], 1u << (16 * (bin & 1)));
        bin = code3 >> 2;
        atomicAdd(&hist[(br * 4 + ((c0 + 3) >> 3)) * 32 + (bin >> 1)], 1u << (16 * (bin & 1)));
    }
    __syncthreads();

    // ---- write out 16 blocks x 64 bins (unpack halfwords) ----
    size_t planeBase = ((size_t)(n * NL1 + ch)) * 256 * NBINS;
    for (int i = tid; i < NHB * NBINS; i += 256) {
        int bl = i >> 6, bin = i & 63;
        unsigned int w = hist[bl * 32 + (bin >> 1)];
        unsigned int cnt = (w >> (16 * (bin & 1))) & 0xFFFFu;
        int br = bl >> 2, bc = bl & 3;
        int blkg = ((P0 >> 3) + br) * 16 + ((Q0 >> 3) + bc);
        out[planeBase + (size_t)blkg * NBINS + bin] = (float)cnt;
    }
}

// =================== Fallback: round-11 fused kernel (82us) ===================
#define C1TAPS(acc0, acc1, acc2, acc3, dp)                                   \
    _Pragma("unroll")                                                        \
    for (int dq = 0; dq < KK; ++dq) {                                        \
        float wa = w1g[(dp) * 7 + dq];                                       \
        float wb = w1g[49 + (dp) * 7 + dq];                                  \
        float wc = w1g[98 + (dp) * 7 + dq];                                  \
        acc0 = __builtin_fmaf(fx0[dq + 0], wa, acc0);                        \
        acc0 = __builtin_fmaf(fx1[dq + 0], wb, acc0);                        \
        acc0 = __builtin_fmaf(fx2[dq + 0], wc, acc0);                        \
        acc1 = __builtin_fmaf(fx0[dq + 1], wa, acc1);                        \
        acc1 = __builtin_fmaf(fx1[dq + 1], wb, acc1);                        \
        acc1 = __builtin_fmaf(fx2[dq + 1], wc, acc1);                        \
        acc2 = __builtin_fmaf(fx0[dq + 2], wa, acc2);                        \
        acc2 = __builtin_fmaf(fx1[dq + 2], wb, acc2);                        \
        acc2 = __builtin_fmaf(fx2[dq + 2], wc, acc2);                        \
        acc3 = __builtin_fmaf(fx0[dq + 3], wa, acc3);                        \
        acc3 = __builtin_fmaf(fx1[dq + 3], wb, acc3);                        \
        acc3 = __builtin_fmaf(fx2[dq + 3], wc, acc3);                        \
    }

#define LDXF(dst, plane, rw, col)                                            \
    { float4 t_;                                                             \
      t_ = *(const float4*)&xt[plane][rw][col];                              \
      dst[0]=t_.x; dst[1]=t_.y; dst[2]=t_.z; dst[3]=t_.w;                    \
      t_ = *(const float4*)&xt[plane][rw][(col)+4];                          \
      dst[4]=t_.x; dst[5]=t_.y; dst[6]=t_.z; dst[7]=t_.w;                    \
      t_ = *(const float4*)&xt[plane][rw][(col)+8];                          \
      dst[8]=t_.x; dst[9]=t_.y; dst[10]=t_.z; dst[11]=t_.w; }

__global__ __launch_bounds__(256, 5) void pcanet_fused(
    const float* __restrict__ x, const float* __restrict__ w1,
    const float* __restrict__ w2, float* __restrict__ out)
{
    const int tid = threadIdx.x;
    const int reg = blockIdx.x;
    const int ch  = blockIdx.y;
    const int n   = blockIdx.z;
    const int P0  = (reg >> 2) * REG;
    const int Q0  = (reg & 3) * REG;

    __shared__ __align__(16) float xt[3][XR][XTP];
    __shared__ __align__(16) float o1[RT][O1P];
    __shared__ unsigned int hist[NHB * 32];

    const float* __restrict__ w1g = w1 + ch * 147;
    const float* __restrict__ w2g = w2;

    {
        const int lane = tid & 63, wv = tid >> 6;
        const float* xn = x + (size_t)n * 3 * IMG * IMG;
        const int gs = Q0 - 6 + lane;
        const bool cok = (gs >= 0) && (gs < IMG);
        if (lane < XTP) {
            for (int c = 0; c < 3; ++c)
                for (int r = wv; r < XR; r += 4) {
                    int gr = P0 - 6 + r;
                    float v = 0.0f;
                    if (cok && gr >= 0 && gr < IMG)
                        v = xn[((size_t)c * IMG + gr) * IMG + gs];
                    xt[c][r][lane] = v;
                }
        }
    }
    for (int i = tid; i < NHB * 32; i += 256) hist[i] = 0u;
    __syncthreads();

    if (tid < 190) {
        int pr = tid / 10, c1 = 4 * (tid % 10), r0 = 2 * pr;
        float a0 = 0.f, a1 = 0.f, a2 = 0.f, a3 = 0.f;
        float b0 = 0.f, b1 = 0.f, b2 = 0.f, b3 = 0.f;
        #pragma unroll
        for (int e = 0; e < 8; ++e) {
            float fx0[12], fx1[12], fx2[12];
            LDXF(fx0, 0, r0 + e, c1)
            LDXF(fx1, 1, r0 + e, c1)
            LDXF(fx2, 2, r0 + e, c1)
            if (e < 7)  { C1TAPS(a0, a1, a2, a3, e) }
            if (e >= 1) { C1TAPS(b0, b1, b2, b3, e - 1) }
        }
        int gs0 = Q0 - 3 + c1;
        bool c0ok = (gs0 + 0 >= 0 && gs0 + 0 < IMG);
        bool c1ok = (gs0 + 1 >= 0 && gs0 + 1 < IMG);
        bool c2ok = (gs0 + 2 >= 0 && gs0 + 2 < IMG);
        bool c3ok = (gs0 + 3 >= 0 && gs0 + 3 < IMG);
        {
            int gr = P0 - 3 + r0;
            bool rok = (gr >= 0 && gr < IMG);
            float4 st;
            st.x = (rok && c0ok) ? a0 : 0.f; st.y = (rok && c1ok) ? a1 : 0.f;
            st.z = (rok && c2ok) ? a2 : 0.f; st.w = (rok && c3ok) ? a3 : 0.f;
            *(float4*)&o1[r0][c1] = st;
        }
        {
            int gr = P0 - 3 + r0 + 1;
            bool rok = (gr >= 0 && gr < IMG);
            float4 st;
            st.x = (rok && c0ok) ? b0 : 0.f; st.y = (rok && c1ok) ? b1 : 0.f;
            st.z = (rok && c2ok) ? b2 : 0.f; st.w = (rok && c3ok) ? b3 : 0.f;
            *(float4*)&o1[r0 + 1][c1] = st;
        }
    }
    __syncthreads();

    {
        const int r  = tid >> 3;
        const int c0 = (tid & 7) * 4;
        float acc[NL2][4];
        #pragma unroll
        for (int l = 0; l < NL2; ++l)
            #pragma unroll
            for (int k = 0; k < 4; ++k) acc[l][k] = 0.f;

        for (int dp = 0; dp < KK; ++dp) {
            float f[12];
            { float4 t_;
              t_ = *(const float4*)&o1[r + dp][c0];
              f[0]=t_.x; f[1]=t_.y; f[2]=t_.z; f[3]=t_.w;
              t_ = *(const float4*)&o1[r + dp][c0 + 4];
              f[4]=t_.x; f[5]=t_.y; f[6]=t_.z; f[7]=t_.w;
              t_ = *(const float4*)&o1[r + dp][c0 + 8];
              f[8]=t_.x; f[9]=t_.y; f[10]=t_.z; f[11]=t_.w; }
            #pragma unroll
            for (int l = 0; l < NL2; ++l)
                #pragma unroll
                for (int dq = 0; dq < KK; ++dq) {
                    float w = w2g[l * 49 + dp * 7 + dq];
                    acc[l][0] = __builtin_fmaf(f[dq + 0], w, acc[l][0]);
                    acc[l][1] = __builtin_fmaf(f[dq + 1], w, acc[l][1]);
                    acc[l][2] = __builtin_fmaf(f[dq + 2], w, acc[l][2]);
                    acc[l][3] = __builtin_fmaf(f[dq + 3], w, acc[l][3]);
                }
        }
        #pragma unroll
        for (int k = 0; k < 4; ++k) {
            int code = 0;
            #pragma unroll
            for (int l = 0; l < NL2; ++l)
                if (acc[l][k] > 0.0f) code |= (1 << l);
            int bin = code >> 2;
            int bc = (c0 + k) >> 3, br = r >> 3;
            atomicAdd(&hist[(br * 4 + bc) * 32 + (bin >> 1)],
                      1u << (16 * (bin & 1)));
        }
    }
    __syncthreads();

    size_t planeBase = ((size_t)(n * NL1 + ch)) * 256 * NBINS;
    for (int i = tid; i < NHB * NBINS; i += 256) {
        int bl = i >> 6, bin = i & 63;
        unsigned int w = hist[bl * 32 + (bin >> 1)];
        unsigned int cnt = (w >> (16 * (bin & 1))) & 0xFFFFu;
        int br = bl >> 2, bc = bl & 3;
        int blkg = ((P0 >> 3) + br) * 16 + ((Q0 >> 3) + bc);
        out[planeBase + (size_t)blkg * NBINS + bin] = (float)cnt;
    }
}

extern "C" void kernel_launch(void* const* d_in, const int* in_sizes, int n_in,
                              void* d_out, int out_size, void* d_ws, size_t ws_size,
                              hipStream_t stream) {
    const float* x  = (const float*)d_in[0];
    const float* w1 = (const float*)d_in[1];
    const float* w2 = (const float*)d_in[2];
    float* out = (float*)d_out;

    const size_t need = (size_t)32 * NL1 * IMG * IMG * sizeof(float);  // 16.8MB
    if (ws_size >= need) {
        float* o1g = (float*)d_ws;
        pcanet_conv1<<<dim3(16, 4, 32),   256, 0, stream>>>(x, w1, o1g);
        pcanet_conv2<<<dim3(16, NL1, 32), 256, 0, stream>>>(o1g, w2, out);
    } else {
        pcanet_fused<<<dim3(16, NL1, 32), 256, 0, stream>>>(x, w1, w2, out);
    }
}